// Round 1
// baseline (303.323 us; speedup 1.0000x reference)
//
#include <hip/hip_runtime.h>
#include <math.h>

#define B_ 16
#define T_ 3000
#define D_ 512
#define NTOK 448
#define NMAX 449
#define LN_EPS 1e-5f

// ws layout (floats):
// [0] c0 = sum(proj_w*beta)+proj_b   [1] pgsum = sum(proj_w*gamma)
// [2..18)  scale[b]
// [18..34) diff[b] = |sum_alpha - tgt|
// [64..64+B*T) cum[b][t]
// total ~192.3 KB

struct F8 { float v[8]; };

__device__ inline F8 load8(const float* __restrict__ p) {
    F8 r;
    float4 a = *(const float4*)p;
    float4 b = *(const float4*)(p + 4);
    r.v[0]=a.x; r.v[1]=a.y; r.v[2]=a.z; r.v[3]=a.w;
    r.v[4]=b.x; r.v[5]=b.y; r.v[6]=b.z; r.v[7]=b.w;
    return r;
}

// ---- Kernel A: tiny constants ----
__global__ __launch_bounds__(512) void k_const(
    const float* __restrict__ projw, const float* __restrict__ gamma,
    const float* __restrict__ beta, const float* __restrict__ projb,
    float* __restrict__ ws)
{
    __shared__ float r0[512], r1[512];
    int d = threadIdx.x;
    r0[d] = projw[d] * beta[d];
    r1[d] = projw[d] * gamma[d];
    __syncthreads();
    for (int off = 256; off > 0; off >>= 1) {
        if (d < off) { r0[d] += r0[d + off]; r1[d] += r1[d + off]; }
        __syncthreads();
    }
    if (d == 0) { ws[0] = r0[0] + projb[0]; ws[1] = r1[0]; }
}

// ---- Kernel B: conv + LN + linear + sigmoid -> alpha[B,T] ----
// 4 waves/block, one t per wave, 8 d per lane.
__global__ __launch_bounds__(256) void k_alpha(
    const float* __restrict__ enc, const float* __restrict__ convw,
    const float* __restrict__ gamma, const float* __restrict__ projw,
    const int* __restrict__ ilen, const float* __restrict__ cst,
    float* __restrict__ alpha_out)
{
    int wave = threadIdx.x >> 6;
    int lane = threadIdx.x & 63;
    int blk  = blockIdx.x;
    int b = blk / (T_ / 4);
    int t = (blk % (T_ / 4)) * 4 + wave;
    int d0 = lane * 8;

    const size_t rowbase = ((size_t)b * T_ + t) * D_ + d0;

    F8 yc = load8(enc + rowbase);
    F8 ym, yp;
    if (t > 0)      ym = load8(enc + rowbase - D_);
    else            { for (int j = 0; j < 8; ++j) ym.v[j] = 0.f; }
    if (t < T_ - 1) yp = load8(enc + rowbase + D_);
    else            { for (int j = 0; j < 8; ++j) yp.v[j] = 0.f; }

    // 24 contiguous conv weights for this lane's 8 channels
    float w24[24];
    const float4* wp = (const float4*)(convw + (size_t)d0 * 3);
#pragma unroll
    for (int i = 0; i < 6; ++i) {
        float4 q = wp[i];
        w24[4*i+0]=q.x; w24[4*i+1]=q.y; w24[4*i+2]=q.z; w24[4*i+3]=q.w;
    }
    F8 pw = load8(projw + d0);
    F8 gm = load8(gamma + d0);

    float s1 = 0.f, s2 = 0.f, sp = 0.f;
#pragma unroll
    for (int j = 0; j < 8; ++j) {
        float y = ym.v[j]*w24[3*j] + yc.v[j]*w24[3*j+1] + yp.v[j]*w24[3*j+2];
        float pg = pw.v[j] * gm.v[j];
        s1 += y; s2 += y*y; sp += pg*y;
    }
#pragma unroll
    for (int off = 1; off < 64; off <<= 1) {
        s1 += __shfl_xor(s1, off);
        s2 += __shfl_xor(s2, off);
        sp += __shfl_xor(sp, off);
    }
    if (lane == 0) {
        float mu  = s1 * (1.0f / D_);
        float var = s2 * (1.0f / D_) - mu * mu;
        float rsig = rsqrtf(var + LN_EPS);
        float logit = rsig * (sp - mu * cst[1]) + cst[0];
        float a = 1.0f / (1.0f + expf(-logit));
        if (t >= ilen[b]) a = 0.0f;
        alpha_out[b * T_ + t] = a;
    }
}

// ---- Kernel C: per-batch sum(alpha) -> scale[b], diff[b] ----
__global__ __launch_bounds__(256) void k_scale(
    const float* __restrict__ alpha, const int* __restrict__ tlen,
    float* __restrict__ ws)
{
    int b = blockIdx.x;
    float s = 0.f;
    for (int t = threadIdx.x; t < T_; t += 256) s += alpha[b * T_ + t];
    __shared__ float red[256];
    red[threadIdx.x] = s;
    __syncthreads();
    for (int off = 128; off > 0; off >>= 1) {
        if (threadIdx.x < off) red[threadIdx.x] += red[threadIdx.x + off];
        __syncthreads();
    }
    if (threadIdx.x == 0) {
        float sum = red[0];
        float tgt = (float)tlen[b];
        ws[2 + b]  = tgt / fmaxf(sum, 1e-8f);
        ws[18 + b] = fabsf(sum - tgt);
    }
}

// ---- Kernel D: per-batch cumsum(alpha*scale) -> cum[b][t]; qty_loss ----
__global__ __launch_bounds__(64) void k_scan(
    const float* __restrict__ alpha, const float* __restrict__ ws,
    float* __restrict__ cum, float* __restrict__ qty)
{
    int b = blockIdx.x;
    int lane = threadIdx.x;
    float scale = ws[2 + b];
    float run = 0.f;
    for (int base = 0; base < T_; base += 64) {
        int t = base + lane;
        float v = (t < T_) ? alpha[b * T_ + t] * scale : 0.f;
#pragma unroll
        for (int off = 1; off < 64; off <<= 1) {
            float n = __shfl_up(v, off);
            if (lane >= off) v += n;
        }
        float cv = run + v;
        if (t < T_) cum[b * T_ + t] = cv;
        run = __shfl(cv, 63);
    }
    if (b == 0 && lane == 0) {
        float q = 0.f;
        for (int i = 0; i < B_; ++i) q += ws[18 + i];
        *qty = q * (1.0f / B_);
    }
}

// ---- Kernel E: gather per (b,k): sum over contributing frames ----
__global__ __launch_bounds__(256) void k_gather(
    const float* __restrict__ enc, const float* __restrict__ cum,
    float* __restrict__ out)
{
    int blk = blockIdx.x;
    int b = blk / NTOK;
    int k = blk % NTOK;
    const float* cb = cum + (size_t)b * T_;

    // lower_bound: first t with cb[t] >= v
    float vk  = (float)k;
    float vk1 = (float)(k + 1);
    int lo = 0, hi = T_;
    while (lo < hi) { int mid = (lo + hi) >> 1; if (cb[mid] < vk) lo = mid + 1; else hi = mid; }
    int a = lo;
    lo = a; hi = T_;
    while (lo < hi) { int mid = (lo + hi) >> 1; if (cb[mid] < vk1) lo = mid + 1; else hi = mid; }
    int e = lo + 1; if (e > T_) e = T_;

    int d0 = threadIdx.x * 2;
    float2 acc = make_float2(0.f, 0.f);
    for (int t = a; t < e; ++t) {
        float cp = (t > 0) ? cb[t - 1] : 0.0f;
        float c  = cb[t];
        int klo = (int)floorf(cp);
        int khi = (int)floorf(c);
        float bnd = (float)(klo + 1);
        float wlo = fmaxf(fminf(c, bnd) - cp, 0.0f);
        float whi = fmaxf(c - bnd, 0.0f);
        float w = 0.0f;
        if (klo == k) w += wlo;
        if (khi == k) w += whi;
        if (w != 0.0f) {
            const float2 ev = *(const float2*)(enc + ((size_t)b * T_ + t) * D_ + d0);
            acc.x += ev.x * w;
            acc.y += ev.y * w;
        }
    }
    *(float2*)(out + ((size_t)b * NTOK + k) * D_ + d0) = acc;
}

extern "C" void kernel_launch(void* const* d_in, const int* in_sizes, int n_in,
                              void* d_out, int out_size, void* d_ws, size_t ws_size,
                              hipStream_t stream) {
    const float* enc   = (const float*)d_in[0];
    const float* convw = (const float*)d_in[1];
    const float* gamma = (const float*)d_in[2];
    const float* beta  = (const float*)d_in[3];
    const float* projw = (const float*)d_in[4];
    const float* projb = (const float*)d_in[5];
    const int*   ilen  = (const int*)d_in[6];
    const int*   tlen  = (const int*)d_in[7];

    float* out_f     = (float*)d_out;                       // [B,448,D]
    float* alpha_out = out_f + (size_t)B_ * NTOK * D_;      // [B,T]
    float* qty_out   = alpha_out + (size_t)B_ * T_;         // scalar

    float* ws  = (float*)d_ws;
    float* cum = ws + 64;                                   // [B,T]

    hipLaunchKernelGGL(k_const, dim3(1), dim3(512), 0, stream,
                       projw, gamma, beta, projb, ws);
    hipLaunchKernelGGL(k_alpha, dim3(B_ * (T_ / 4)), dim3(256), 0, stream,
                       enc, convw, gamma, projw, ilen, ws, alpha_out);
    hipLaunchKernelGGL(k_scale, dim3(B_), dim3(256), 0, stream,
                       alpha_out, tlen, ws);
    hipLaunchKernelGGL(k_scan, dim3(B_), dim3(64), 0, stream,
                       alpha_out, ws, cum, qty_out);
    hipLaunchKernelGGL(k_gather, dim3(B_ * NTOK), dim3(256), 0, stream,
                       enc, cum, out_f);
}

// Round 2
// 217.465 us; speedup vs baseline: 1.3948x; 1.3948x over previous
//
#include <hip/hip_runtime.h>
#include <math.h>

#define B_ 16
#define T_ 3000
#define D_ 512
#define NTOK 448
#define NMAX 449
#define LN_EPS 1e-5f

// ws layout (floats):
// [0] c0 = sum(proj_w*beta)+proj_b   [1] pgsum = sum(proj_w*gamma)
// [16..32)  diff[b] = |sum_alpha - tgt|
// [64..64+B*T)  cum[b][t]
// [64+B*T ...)  start[b][450]  (ints)

#define WS_DIFF 16
#define WS_CUM  64
#define WS_START (64 + B_ * T_)

struct F8 { float v[8]; };

__device__ inline F8 load8(const float* __restrict__ p) {
    F8 r;
    float4 a = *(const float4*)p;
    float4 b = *(const float4*)(p + 4);
    r.v[0]=a.x; r.v[1]=a.y; r.v[2]=a.z; r.v[3]=a.w;
    r.v[4]=b.x; r.v[5]=b.y; r.v[6]=b.z; r.v[7]=b.w;
    return r;
}

// ---- Kernel A: tiny constants ----
__global__ __launch_bounds__(512) void k_const(
    const float* __restrict__ projw, const float* __restrict__ gamma,
    const float* __restrict__ beta, const float* __restrict__ projb,
    float* __restrict__ ws)
{
    __shared__ float r0[512], r1[512];
    int d = threadIdx.x;
    r0[d] = projw[d] * beta[d];
    r1[d] = projw[d] * gamma[d];
    __syncthreads();
    for (int off = 256; off > 0; off >>= 1) {
        if (d < off) { r0[d] += r0[d + off]; r1[d] += r1[d + off]; }
        __syncthreads();
    }
    if (d == 0) { ws[0] = r0[0] + projb[0]; ws[1] = r1[0]; }
}

// ---- Kernel B: conv + LN + linear + sigmoid -> alpha[B,T] ----
// Each wave handles 4 consecutive t (6 row loads per 4 outputs).
// Block = 4 waves = 16 t. Grid = B * ceil(T/16) = B * 188.
__global__ __launch_bounds__(256) void k_alpha(
    const float* __restrict__ enc, const float* __restrict__ convw,
    const float* __restrict__ gamma, const float* __restrict__ projw,
    const int* __restrict__ ilen, const float* __restrict__ cst,
    float* __restrict__ alpha_out)
{
    const int NB = 188;  // blocks per batch
    int wave = threadIdx.x >> 6;
    int lane = threadIdx.x & 63;
    int b  = blockIdx.x / NB;
    int tb = blockIdx.x % NB;
    int t0 = tb * 16 + wave * 4;          // this wave: t0 .. t0+3
    int d0 = lane * 8;
    if (t0 >= T_) return;

    const float* rowp = enc + ((size_t)b * T_ + t0) * D_ + d0;

    F8 r[6];
#pragma unroll
    for (int i = 0; i < 6; ++i) {
        int t = t0 - 1 + i;
        if (t >= 0 && t < T_) r[i] = load8(rowp + (ptrdiff_t)(i - 1) * D_);
        else { for (int j = 0; j < 8; ++j) r[i].v[j] = 0.f; }
    }

    float w24[24];
    const float4* wp = (const float4*)(convw + (size_t)d0 * 3);
#pragma unroll
    for (int i = 0; i < 6; ++i) {
        float4 q = wp[i];
        w24[4*i+0]=q.x; w24[4*i+1]=q.y; w24[4*i+2]=q.z; w24[4*i+3]=q.w;
    }
    F8 pw = load8(projw + d0);
    F8 gm = load8(gamma + d0);
    float pg[8];
#pragma unroll
    for (int j = 0; j < 8; ++j) pg[j] = pw.v[j] * gm.v[j];

    float s1[4], s2[4], sp[4];
#pragma unroll
    for (int q = 0; q < 4; ++q) { s1[q]=0.f; s2[q]=0.f; sp[q]=0.f; }

#pragma unroll
    for (int q = 0; q < 4; ++q) {
#pragma unroll
        for (int j = 0; j < 8; ++j) {
            float y = r[q].v[j]*w24[3*j] + r[q+1].v[j]*w24[3*j+1] + r[q+2].v[j]*w24[3*j+2];
            s1[q] += y; s2[q] += y*y; sp[q] += pg[j]*y;
        }
    }
#pragma unroll
    for (int off = 1; off < 64; off <<= 1) {
#pragma unroll
        for (int q = 0; q < 4; ++q) {
            s1[q] += __shfl_xor(s1[q], off);
            s2[q] += __shfl_xor(s2[q], off);
            sp[q] += __shfl_xor(sp[q], off);
        }
    }
    if (lane == 0) {
        int il = ilen[b];
        float c0 = cst[0], c1 = cst[1];
#pragma unroll
        for (int q = 0; q < 4; ++q) {
            int t = t0 + q;
            if (t >= T_) break;
            float mu  = s1[q] * (1.0f / D_);
            float var = s2[q] * (1.0f / D_) - mu * mu;
            float rsig = rsqrtf(var + LN_EPS);
            float logit = rsig * (sp[q] - mu * c1) + c0;
            float a = 1.0f / (1.0f + expf(-logit));
            if (t >= il) a = 0.0f;
            alpha_out[b * T_ + t] = a;
        }
    }
}

// ---- Kernel C: per-batch sum + cumsum + bin starts (all in LDS) ----
__global__ __launch_bounds__(512) void k_prep(
    const float* __restrict__ alpha, const int* __restrict__ tlen,
    float* __restrict__ ws)
{
    __shared__ float sc[T_];
    __shared__ float red[512];
    __shared__ float part[8];

    int b = blockIdx.x;
    int tid = threadIdx.x;
    int wave = tid >> 6;
    int lane = tid & 63;

    float* cumg = ws + WS_CUM + (size_t)b * T_;
    int*   stg  = (int*)(ws + WS_START) + b * 450;

    float s = 0.f;
    for (int t = tid; t < T_; t += 512) { float a = alpha[b * T_ + t]; sc[t] = a; s += a; }
    red[tid] = s;
    __syncthreads();
    for (int off = 256; off > 0; off >>= 1) {
        if (tid < off) red[tid] += red[tid + off];
        __syncthreads();
    }
    float sum = red[0];
    float tgt = (float)tlen[b];
    float scale = tgt / fmaxf(sum, 1e-8f);
    if (tid == 0) ws[WS_DIFF + b] = fabsf(sum - tgt);
    __syncthreads();

    // block-wide inclusive cumsum of sc*scale
    float run = 0.f;
    for (int base = 0; base < T_; base += 512) {
        int t = base + tid;
        float v = (t < T_) ? sc[t] * scale : 0.f;
#pragma unroll
        for (int off = 1; off < 64; off <<= 1) {
            float n = __shfl_up(v, off);
            if (lane >= off) v += n;
        }
        if (lane == 63) part[wave] = v;
        __syncthreads();
        float prefix = run;
        for (int w = 0; w < 8; ++w) {
            float pv = part[w];
            if (w < wave) prefix += pv;
            run += pv;
        }
        v += prefix;
        if (t < T_) { sc[t] = v; cumg[t] = v; }
        __syncthreads();
    }

    // bin starts: start[k] = first t with cum[t] >= k, for k in [0,449]
    for (int k = tid; k < 450; k += 512) {
        float vk = (float)k;
        int lo = 0, hi = T_;
        while (lo < hi) {
            int mid = (lo + hi) >> 1;
            if (sc[mid] < vk) lo = mid + 1; else hi = mid;
        }
        stg[k] = lo;
    }
}

// ---- Kernel D: qty loss ----
__global__ __launch_bounds__(64) void k_qty(
    const float* __restrict__ ws, float* __restrict__ qty)
{
    if (threadIdx.x == 0) {
        float q = 0.f;
        for (int i = 0; i < B_; ++i) q += ws[WS_DIFF + i];
        *qty = q * (1.0f / B_);
    }
}

// ---- Kernel E: gather per (b,k) ----
__global__ __launch_bounds__(256) void k_gather(
    const float* __restrict__ enc, const float* __restrict__ ws,
    float* __restrict__ out)
{
    int blk = blockIdx.x;
    int b = blk / NTOK;
    int k = blk % NTOK;

    const float* cb = ws + WS_CUM + (size_t)b * T_;
    const int*   stg = (const int*)(ws + WS_START) + b * 450;

    int a = stg[k];
    int e = stg[k + 1] + 1;
    if (e > T_) e = T_;

    int d0 = threadIdx.x * 2;
    const float* encb = enc + ((size_t)b * T_) * D_ + d0;
    float accx = 0.f, accy = 0.f;

    __shared__ float scum[257];

    for (int base = a; base < e; base += 256) {
        int nf = e - base; if (nf > 256) nf = 256;
        int i = threadIdx.x;
        if (i <= nf) {
            int t = base - 1 + i;
            scum[i] = (t >= 0) ? cb[t] : 0.0f;
        }
        __syncthreads();

        for (int j = 0; j < nf; j += 4) {
            float w[4];
#pragma unroll
            for (int u = 0; u < 4; ++u) {
                w[u] = 0.f;
                if (j + u < nf) {
                    float cp = scum[j + u], c = scum[j + u + 1];
                    int klo = (int)floorf(cp);
                    int khi = (int)floorf(c);
                    float bnd = (float)(klo + 1);
                    float ww = 0.f;
                    if (klo == k) ww += fmaxf(fminf(c, bnd) - cp, 0.f);
                    if (khi == k) ww += fmaxf(c - bnd, 0.f);
                    w[u] = ww;
                }
            }
            float2 v[4];
#pragma unroll
            for (int u = 0; u < 4; ++u) {
                v[u] = make_float2(0.f, 0.f);
                if (w[u] != 0.f)
                    v[u] = *(const float2*)(encb + (size_t)(base + j + u) * D_);
            }
#pragma unroll
            for (int u = 0; u < 4; ++u) {
                accx += v[u].x * w[u];
                accy += v[u].y * w[u];
            }
        }
        __syncthreads();
    }

    float2 res = make_float2(accx, accy);
    *(float2*)(out + ((size_t)b * NTOK + k) * D_ + d0) = res;
}

extern "C" void kernel_launch(void* const* d_in, const int* in_sizes, int n_in,
                              void* d_out, int out_size, void* d_ws, size_t ws_size,
                              hipStream_t stream) {
    const float* enc   = (const float*)d_in[0];
    const float* convw = (const float*)d_in[1];
    const float* gamma = (const float*)d_in[2];
    const float* beta  = (const float*)d_in[3];
    const float* projw = (const float*)d_in[4];
    const float* projb = (const float*)d_in[5];
    const int*   ilen  = (const int*)d_in[6];
    const int*   tlen  = (const int*)d_in[7];

    float* out_f     = (float*)d_out;                       // [B,448,D]
    float* alpha_out = out_f + (size_t)B_ * NTOK * D_;      // [B,T]
    float* qty_out   = alpha_out + (size_t)B_ * T_;         // scalar

    float* ws = (float*)d_ws;

    hipLaunchKernelGGL(k_const, dim3(1), dim3(512), 0, stream,
                       projw, gamma, beta, projb, ws);
    hipLaunchKernelGGL(k_alpha, dim3(B_ * 188), dim3(256), 0, stream,
                       enc, convw, gamma, projw, ilen, ws, alpha_out);
    hipLaunchKernelGGL(k_prep, dim3(B_), dim3(512), 0, stream,
                       alpha_out, tlen, ws);
    hipLaunchKernelGGL(k_qty, dim3(1), dim3(64), 0, stream,
                       ws, qty_out);
    hipLaunchKernelGGL(k_gather, dim3(B_ * NTOK), dim3(256), 0, stream,
                       enc, ws, out_f);
}

// Round 3
// 55.963 us; speedup vs baseline: 5.4201x; 3.8859x over previous
//
#include <hip/hip_runtime.h>
#include <math.h>

#define B_ 16
#define T_ 3000
#define D_ 512
#define NTOK 448
#define LN_EPS 1e-5f

// ws layout (floats):
// [0] c0 = sum(proj_w*beta)+proj_b   [1] pgsum = sum(proj_w*gamma)
// [16..32)  diff[b] = |sum_alpha - tgt|
// [64..64+B*T)        cum[b][t]
// [64+B*T .. +B*450)  stg[b][450] (ints)
#define WS_DIFF 16
#define WS_CUM  64
#define WS_STG  (64 + B_ * T_)

struct F8 { float v[8]; };

__device__ inline F8 load8(const float* __restrict__ p) {
    F8 r;
    float4 a = *(const float4*)p;
    float4 b = *(const float4*)(p + 4);
    r.v[0]=a.x; r.v[1]=a.y; r.v[2]=a.z; r.v[3]=a.w;
    r.v[4]=b.x; r.v[5]=b.y; r.v[6]=b.z; r.v[7]=b.w;
    return r;
}

// ---- Kernel A: tiny constants ----
__global__ __launch_bounds__(512) void k_const(
    const float* __restrict__ projw, const float* __restrict__ gamma,
    const float* __restrict__ beta, const float* __restrict__ projb,
    float* __restrict__ ws)
{
    __shared__ float r0[512], r1[512];
    int d = threadIdx.x;
    r0[d] = projw[d] * beta[d];
    r1[d] = projw[d] * gamma[d];
    __syncthreads();
    for (int off = 256; off > 0; off >>= 1) {
        if (d < off) { r0[d] += r0[d + off]; r1[d] += r1[d + off]; }
        __syncthreads();
    }
    if (d == 0) { ws[0] = r0[0] + projb[0]; ws[1] = r1[0]; }
}

// ---- Kernel B: conv + LN + linear + sigmoid -> alpha[B,T] ----
__global__ __launch_bounds__(256) void k_alpha(
    const float* __restrict__ enc, const float* __restrict__ convw,
    const float* __restrict__ gamma, const float* __restrict__ projw,
    const int* __restrict__ ilen, const float* __restrict__ cst,
    float* __restrict__ alpha_out)
{
    const int NB = 188;  // blocks per batch
    int wave = threadIdx.x >> 6;
    int lane = threadIdx.x & 63;
    int b  = blockIdx.x / NB;
    int tb = blockIdx.x % NB;
    int t0 = tb * 16 + wave * 4;          // this wave: t0 .. t0+3
    int d0 = lane * 8;
    if (t0 >= T_) return;

    const float* rowp = enc + ((size_t)b * T_ + t0) * D_ + d0;

    F8 r[6];
#pragma unroll
    for (int i = 0; i < 6; ++i) {
        int t = t0 - 1 + i;
        if (t >= 0 && t < T_) r[i] = load8(rowp + (ptrdiff_t)(i - 1) * D_);
        else { for (int j = 0; j < 8; ++j) r[i].v[j] = 0.f; }
    }

    float w24[24];
    const float4* wp = (const float4*)(convw + (size_t)d0 * 3);
#pragma unroll
    for (int i = 0; i < 6; ++i) {
        float4 q = wp[i];
        w24[4*i+0]=q.x; w24[4*i+1]=q.y; w24[4*i+2]=q.z; w24[4*i+3]=q.w;
    }
    F8 pw = load8(projw + d0);
    F8 gm = load8(gamma + d0);
    float pg[8];
#pragma unroll
    for (int j = 0; j < 8; ++j) pg[j] = pw.v[j] * gm.v[j];

    float s1[4], s2[4], sp[4];
#pragma unroll
    for (int q = 0; q < 4; ++q) { s1[q]=0.f; s2[q]=0.f; sp[q]=0.f; }

#pragma unroll
    for (int q = 0; q < 4; ++q) {
#pragma unroll
        for (int j = 0; j < 8; ++j) {
            float y = r[q].v[j]*w24[3*j] + r[q+1].v[j]*w24[3*j+1] + r[q+2].v[j]*w24[3*j+2];
            s1[q] += y; s2[q] += y*y; sp[q] += pg[j]*y;
        }
    }
#pragma unroll
    for (int off = 1; off < 64; off <<= 1) {
#pragma unroll
        for (int q = 0; q < 4; ++q) {
            s1[q] += __shfl_xor(s1[q], off);
            s2[q] += __shfl_xor(s2[q], off);
            sp[q] += __shfl_xor(sp[q], off);
        }
    }
    if (lane == 0) {
        int il = ilen[b];
        float c0 = cst[0], c1 = cst[1];
#pragma unroll
        for (int q = 0; q < 4; ++q) {
            int t = t0 + q;
            if (t >= T_) break;
            float mu  = s1[q] * (1.0f / D_);
            float var = s2[q] * (1.0f / D_) - mu * mu;
            float rsig = rsqrtf(var + LN_EPS);
            float logit = rsig * (sp[q] - mu * c1) + c0;
            float a = 1.0f / (1.0f + expf(-logit));
            if (t >= il) a = 0.0f;
            alpha_out[b * T_ + t] = a;
        }
    }
}

// ---- Kernel C: per-batch sum + cumsum + bin starts (all in LDS) ----
__global__ __launch_bounds__(512) void k_prep(
    const float* __restrict__ alpha, const int* __restrict__ tlen,
    float* __restrict__ ws)
{
    __shared__ float sc[T_];
    __shared__ float red[512];
    __shared__ float part[8];

    int b = blockIdx.x;
    int tid = threadIdx.x;
    int wave = tid >> 6;
    int lane = tid & 63;

    float* cumg = ws + WS_CUM + (size_t)b * T_;
    int*   stg  = (int*)(ws + WS_STG) + b * 450;

    float s = 0.f;
    for (int t = tid; t < T_; t += 512) { float a = alpha[b * T_ + t]; sc[t] = a; s += a; }
    red[tid] = s;
    __syncthreads();
    for (int off = 256; off > 0; off >>= 1) {
        if (tid < off) red[tid] += red[tid + off];
        __syncthreads();
    }
    float sum = red[0];
    float tgt = (float)tlen[b];
    float scale = tgt / fmaxf(sum, 1e-8f);
    if (tid == 0) ws[WS_DIFF + b] = fabsf(sum - tgt);
    __syncthreads();

    // block-wide inclusive cumsum of sc*scale
    float run = 0.f;
    for (int base = 0; base < T_; base += 512) {
        int t = base + tid;
        float v = (t < T_) ? sc[t] * scale : 0.f;
#pragma unroll
        for (int off = 1; off < 64; off <<= 1) {
            float n = __shfl_up(v, off);
            if (lane >= off) v += n;
        }
        if (lane == 63) part[wave] = v;
        __syncthreads();
        float prefix = run;
        for (int w = 0; w < 8; ++w) {
            float pv = part[w];
            if (w < wave) prefix += pv;
            run += pv;
        }
        v += prefix;
        if (t < T_) { sc[t] = v; cumg[t] = v; }
        __syncthreads();
    }

    // bin starts: stg[k] = first t with cum[t] >= k, k in [0,449]
    for (int k = tid; k < 450; k += 512) {
        float vk = (float)k;
        int lo = 0, hi = T_;
        while (lo < hi) {
            int mid = (lo + hi) >> 1;
            if (sc[mid] < vk) lo = mid + 1; else hi = mid;
        }
        stg[k] = lo;
    }
}

// ---- Kernel D: qty loss ----
__global__ __launch_bounds__(64) void k_qty(
    const float* __restrict__ ws, float* __restrict__ qty)
{
    if (threadIdx.x == 0) {
        float q = 0.f;
        for (int i = 0; i < B_; ++i) q += ws[WS_DIFF + i];
        *qty = q * (1.0f / B_);
    }
}

// ---- Kernel E: gather, one WAVE per 2 bins (no block syncs) ----
// Block = 4 waves = 8 bins. Grid = B * 56.
__global__ __launch_bounds__(256) void k_gather(
    const float* __restrict__ enc, const float* __restrict__ ws,
    const int* __restrict__ ilen, float* __restrict__ out)
{
    const int NBLK = NTOK / 8;  // 56
    int b  = blockIdx.x / NBLK;
    int kg = blockIdx.x % NBLK;
    int wave = threadIdx.x >> 6;
    int lane = threadIdx.x & 63;
    int k0 = kg * 8 + wave * 2;          // this wave: bins k0, k0+1

    const float* cb  = ws + WS_CUM + (size_t)b * T_;
    const int*   stg = (const int*)(ws + WS_STG) + b * 450;

    int il = ilen[b];
    int a = stg[k0];
    int e = stg[k0 + 2] + 1;
    if (e > il) e = il;                  // frames >= il have zero weight

    int d0 = lane * 8;
    const float* encb = enc + (size_t)b * T_ * D_ + d0;

    float4 a0a = {0,0,0,0}, a0b = {0,0,0,0};
    float4 a1a = {0,0,0,0}, a1b = {0,0,0,0};

    float fk0 = (float)k0, fk1 = (float)(k0 + 1);

    for (int base = a; base < e; base += 32) {
        int n = e - base; if (n > 32) n = 32;
        // lanes 0..n hold cum[base-1 .. base+n-1]
        float cl = 0.0f;
        int t = base - 1 + lane;
        if (lane <= n && t >= 0) cl = cb[t];

        for (int j = 0; j < n; ++j) {
            float cp = __shfl(cl, j);
            float c  = __shfl(cl, j + 1);
            float fklo = floorf(cp);
            float fkhi = floorf(c);
            float bnd  = fklo + 1.0f;
            float wlo  = fmaxf(fminf(c, bnd) - cp, 0.0f);
            float whi  = fmaxf(c - bnd, 0.0f);
            float w0 = (fklo == fk0 ? wlo : 0.0f) + (fkhi == fk0 ? whi : 0.0f);
            float w1 = (fklo == fk1 ? wlo : 0.0f) + (fkhi == fk1 ? whi : 0.0f);
            if (w0 != 0.0f || w1 != 0.0f) {      // wave-uniform branch
                const float* rp = encb + (size_t)(base + j) * D_;
                float4 ea = *(const float4*)rp;
                float4 eb = *(const float4*)(rp + 4);
                a0a.x += ea.x*w0; a0a.y += ea.y*w0; a0a.z += ea.z*w0; a0a.w += ea.w*w0;
                a0b.x += eb.x*w0; a0b.y += eb.y*w0; a0b.z += eb.z*w0; a0b.w += eb.w*w0;
                a1a.x += ea.x*w1; a1a.y += ea.y*w1; a1a.z += ea.z*w1; a1a.w += ea.w*w1;
                a1b.x += eb.x*w1; a1b.y += eb.y*w1; a1b.z += eb.z*w1; a1b.w += eb.w*w1;
            }
        }
    }

    float* op = out + ((size_t)b * NTOK + k0) * D_ + d0;
    *(float4*)op        = a0a;
    *(float4*)(op + 4)  = a0b;
    *(float4*)(op + D_)     = a1a;
    *(float4*)(op + D_ + 4) = a1b;
}

extern "C" void kernel_launch(void* const* d_in, const int* in_sizes, int n_in,
                              void* d_out, int out_size, void* d_ws, size_t ws_size,
                              hipStream_t stream) {
    const float* enc   = (const float*)d_in[0];
    const float* convw = (const float*)d_in[1];
    const float* gamma = (const float*)d_in[2];
    const float* beta  = (const float*)d_in[3];
    const float* projw = (const float*)d_in[4];
    const float* projb = (const float*)d_in[5];
    const int*   ilen  = (const int*)d_in[6];
    const int*   tlen  = (const int*)d_in[7];

    float* out_f     = (float*)d_out;                       // [B,448,D]
    float* alpha_out = out_f + (size_t)B_ * NTOK * D_;      // [B,T]
    float* qty_out   = alpha_out + (size_t)B_ * T_;         // scalar

    float* ws = (float*)d_ws;

    hipLaunchKernelGGL(k_const, dim3(1), dim3(512), 0, stream,
                       projw, gamma, beta, projb, ws);
    hipLaunchKernelGGL(k_alpha, dim3(B_ * 188), dim3(256), 0, stream,
                       enc, convw, gamma, projw, ilen, ws, alpha_out);
    hipLaunchKernelGGL(k_prep, dim3(B_), dim3(512), 0, stream,
                       alpha_out, tlen, ws);
    hipLaunchKernelGGL(k_qty, dim3(1), dim3(64), 0, stream,
                       ws, qty_out);
    hipLaunchKernelGGL(k_gather, dim3(B_ * (NTOK / 8)), dim3(256), 0, stream,
                       enc, ws, ilen, out_f);
}

// Round 4
// 51.361 us; speedup vs baseline: 5.9057x; 1.0896x over previous
//
#include <hip/hip_runtime.h>
#include <math.h>

#define B_ 16
#define T_ 3000
#define D_ 512
#define NTOK 448
#define LN_EPS 1e-5f

// ws layout (floats):
// [16..32)  diff[b] = |sum_alpha - tgt|
// [64..64+B*T)        cum[b][t]
// [64+B*T .. )        stg[b][450] (ints)
#define WS_DIFF 16
#define WS_CUM  64
#define WS_STG  (64 + B_ * T_)

struct F8 { float v[8]; };

__device__ inline F8 load8(const float* __restrict__ p) {
    F8 r;
    float4 a = *(const float4*)p;
    float4 b = *(const float4*)(p + 4);
    r.v[0]=a.x; r.v[1]=a.y; r.v[2]=a.z; r.v[3]=a.w;
    r.v[4]=b.x; r.v[5]=b.y; r.v[6]=b.z; r.v[7]=b.w;
    return r;
}

// ---- Kernel B: conv + LN + linear + sigmoid -> alpha[B,T] (const fused) ----
__global__ __launch_bounds__(256) void k_alpha(
    const float* __restrict__ enc, const float* __restrict__ convw,
    const float* __restrict__ gamma, const float* __restrict__ beta,
    const float* __restrict__ projw, const float* __restrict__ projb,
    const int* __restrict__ ilen, float* __restrict__ alpha_out)
{
    const int NB = 188;  // blocks per batch
    int wave = threadIdx.x >> 6;
    int lane = threadIdx.x & 63;
    int b  = blockIdx.x / NB;
    int tb = blockIdx.x % NB;
    int t0 = tb * 16 + wave * 4;          // this wave: t0 .. t0+3
    int d0 = lane * 8;
    if (t0 >= T_) return;

    const float* rowp = enc + ((size_t)b * T_ + t0) * D_ + d0;

    F8 r[6];
#pragma unroll
    for (int i = 0; i < 6; ++i) {
        int t = t0 - 1 + i;
        if (t >= 0 && t < T_) r[i] = load8(rowp + (ptrdiff_t)(i - 1) * D_);
        else { for (int j = 0; j < 8; ++j) r[i].v[j] = 0.f; }
    }

    float w24[24];
    const float4* wp = (const float4*)(convw + (size_t)d0 * 3);
#pragma unroll
    for (int i = 0; i < 6; ++i) {
        float4 q = wp[i];
        w24[4*i+0]=q.x; w24[4*i+1]=q.y; w24[4*i+2]=q.z; w24[4*i+3]=q.w;
    }
    F8 pw = load8(projw + d0);
    F8 gm = load8(gamma + d0);
    F8 bt = load8(beta + d0);
    float pg[8];
    float c0p = 0.f, c1p = 0.f;
#pragma unroll
    for (int j = 0; j < 8; ++j) {
        pg[j] = pw.v[j] * gm.v[j];
        c0p += pw.v[j] * bt.v[j];
        c1p += pg[j];
    }

    float s1[4], s2[4], sp[4];
#pragma unroll
    for (int q = 0; q < 4; ++q) { s1[q]=0.f; s2[q]=0.f; sp[q]=0.f; }

#pragma unroll
    for (int q = 0; q < 4; ++q) {
#pragma unroll
        for (int j = 0; j < 8; ++j) {
            float y = r[q].v[j]*w24[3*j] + r[q+1].v[j]*w24[3*j+1] + r[q+2].v[j]*w24[3*j+2];
            s1[q] += y; s2[q] += y*y; sp[q] += pg[j]*y;
        }
    }
#pragma unroll
    for (int off = 1; off < 64; off <<= 1) {
#pragma unroll
        for (int q = 0; q < 4; ++q) {
            s1[q] += __shfl_xor(s1[q], off);
            s2[q] += __shfl_xor(s2[q], off);
            sp[q] += __shfl_xor(sp[q], off);
        }
        c0p += __shfl_xor(c0p, off);
        c1p += __shfl_xor(c1p, off);
    }
    if (lane == 0) {
        int il = ilen[b];
        float c0 = c0p + projb[0];
        float c1 = c1p;
#pragma unroll
        for (int q = 0; q < 4; ++q) {
            int t = t0 + q;
            if (t >= T_) break;
            float mu  = s1[q] * (1.0f / D_);
            float var = s2[q] * (1.0f / D_) - mu * mu;
            float rsig = rsqrtf(var + LN_EPS);
            float logit = rsig * (sp[q] - mu * c1) + c0;
            float a = 1.0f / (1.0f + expf(-logit));
            if (t >= il) a = 0.0f;
            alpha_out[b * T_ + t] = a;
        }
    }
}

// ---- Kernel C: per-batch scan + scale + bin starts (single LDS pass) ----
__global__ __launch_bounds__(512) void k_prep(
    const float* __restrict__ alpha, const int* __restrict__ tlen,
    float* __restrict__ ws)
{
    __shared__ float sc[T_];
    __shared__ float part[8];

    int b = blockIdx.x;
    int tid = threadIdx.x;
    int wave = tid >> 6;
    int lane = tid & 63;

    float* cumg = ws + WS_CUM + (size_t)b * T_;
    int*   stg  = (int*)(ws + WS_STG) + b * 450;

    // block-wide inclusive cumsum of alpha (unscaled)
    float run = 0.f;
    for (int base = 0; base < T_; base += 512) {
        int t = base + tid;
        float v = (t < T_) ? alpha[b * T_ + t] : 0.f;
#pragma unroll
        for (int off = 1; off < 64; off <<= 1) {
            float n = __shfl_up(v, off);
            if (lane >= off) v += n;
        }
        if (lane == 63) part[wave] = v;
        __syncthreads();
        float prefix = run;
        for (int w = 0; w < 8; ++w) {
            float pv = part[w];
            if (w < wave) prefix += pv;
            run += pv;
        }
        v += prefix;
        if (t < T_) sc[t] = v;
        __syncthreads();
    }

    float sum = run;               // identical in all threads
    float tgt = (float)tlen[b];
    float scale = tgt / fmaxf(sum, 1e-8f);
    if (tid == 0) ws[WS_DIFF + b] = fabsf(sum - tgt);

    // scale in LDS + write to global
    for (int t = tid; t < T_; t += 512) {
        float cv = sc[t] * scale;
        sc[t] = cv;
        cumg[t] = cv;
    }
    __syncthreads();

    // bin starts: stg[k] = first t with cum[t] >= k, k in [0,449]
    for (int k = tid; k < 450; k += 512) {
        float vk = (float)k;
        int lo = 0, hi = T_;
        while (lo < hi) {
            int mid = (lo + hi) >> 1;
            if (sc[mid] < vk) lo = mid + 1; else hi = mid;
        }
        stg[k] = lo;
    }
}

// ---- Kernel E: gather, one WAVE per bin, branch-free inner loop ----
// Block = 4 waves = 4 bins. Grid = B*112 + 1 (last block: qty loss).
__global__ __launch_bounds__(256) void k_gather(
    const float* __restrict__ enc, const float* __restrict__ ws,
    const int* __restrict__ ilen, float* __restrict__ out,
    float* __restrict__ qty)
{
    int bid = blockIdx.x;
    if (bid == B_ * 112) {               // qty block
        int lane = threadIdx.x;
        if (lane < 64) {
            float v = (lane < B_) ? ws[WS_DIFF + lane] : 0.f;
#pragma unroll
            for (int off = 1; off < 16; off <<= 1) v += __shfl_xor(v, off);
            if (lane == 0) *qty = v * (1.0f / B_);
        }
        return;
    }

    const int NBLK = NTOK / 4;  // 112
    int b  = bid / NBLK;
    int kg = bid % NBLK;
    int wave = threadIdx.x >> 6;
    int lane = threadIdx.x & 63;
    int k = kg * 4 + wave;

    const float* cb  = ws + WS_CUM + (size_t)b * T_;
    const int*   stg = (const int*)(ws + WS_STG) + b * 450;

    int il = ilen[b];
    int a = stg[k];
    int e = stg[k + 1] + 1;
    if (e > il) e = il;                  // frames >= il carry zero weight

    int d0 = lane * 8;
    const float* encb = enc + (size_t)b * T_ * D_ + d0;

    float4 aa = {0,0,0,0}, ab = {0,0,0,0};
    float fk = (float)k;

    for (int base = a; base < e; base += 63) {
        int n = e - base; if (n > 63) n = 63;
        // lane j (j<=n) holds cum[base-1+j]; weight of frame base+j for bin k:
        float cl = 0.0f;
        int t = base - 1 + lane;
        if (lane <= n && t >= 0) cl = cb[t];
        float cn = __shfl_down(cl, 1);
        float fklo = floorf(cl);
        float bnd  = fklo + 1.0f;
        float wlo  = fmaxf(fminf(cn, bnd) - cl, 0.0f);
        float whi  = fmaxf(cn - bnd, 0.0f);
        float wl = (fklo == fk ? wlo : 0.0f) + (floorf(cn) == fk ? whi : 0.0f);
        if (lane >= n) wl = 0.0f;

#pragma unroll 4
        for (int j = 0; j < n; ++j) {
            float w = __shfl(wl, j);
            const float* rp = encb + (size_t)(base + j) * D_;
            float4 ea = *(const float4*)rp;
            float4 eb = *(const float4*)(rp + 4);
            aa.x += ea.x*w; aa.y += ea.y*w; aa.z += ea.z*w; aa.w += ea.w*w;
            ab.x += eb.x*w; ab.y += eb.y*w; ab.z += eb.z*w; ab.w += eb.w*w;
        }
    }

    float* op = out + ((size_t)b * NTOK + k) * D_ + d0;
    *(float4*)op       = aa;
    *(float4*)(op + 4) = ab;
}

extern "C" void kernel_launch(void* const* d_in, const int* in_sizes, int n_in,
                              void* d_out, int out_size, void* d_ws, size_t ws_size,
                              hipStream_t stream) {
    const float* enc   = (const float*)d_in[0];
    const float* convw = (const float*)d_in[1];
    const float* gamma = (const float*)d_in[2];
    const float* beta  = (const float*)d_in[3];
    const float* projw = (const float*)d_in[4];
    const float* projb = (const float*)d_in[5];
    const int*   ilen  = (const int*)d_in[6];
    const int*   tlen  = (const int*)d_in[7];

    float* out_f     = (float*)d_out;                       // [B,448,D]
    float* alpha_out = out_f + (size_t)B_ * NTOK * D_;      // [B,T]
    float* qty_out   = alpha_out + (size_t)B_ * T_;         // scalar

    float* ws = (float*)d_ws;

    hipLaunchKernelGGL(k_alpha, dim3(B_ * 188), dim3(256), 0, stream,
                       enc, convw, gamma, beta, projw, projb, ilen, alpha_out);
    hipLaunchKernelGGL(k_prep, dim3(B_), dim3(512), 0, stream,
                       alpha_out, tlen, ws);
    hipLaunchKernelGGL(k_gather, dim3(B_ * 112 + 1), dim3(256), 0, stream,
                       enc, ws, ilen, out_f, qty_out);
}

// Round 5
// 48.072 us; speedup vs baseline: 6.3097x; 1.0684x over previous
//
#include <hip/hip_runtime.h>
#include <math.h>

#define B_ 16
#define T_ 3000
#define D_ 512
#define NTOK 448
#define LN_EPS 1e-5f

// ws layout (floats):
// [16..32)   diff[b] = |sum_alpha - tgt|
// [64..64+B*T)   cum[b][t]
// [64+B*T ..)    ae[b][448] (int2: start, end)
#define WS_DIFF 16
#define WS_CUM  64
#define WS_AE   (64 + B_ * T_)

struct F8 { float v[8]; };

__device__ inline F8 load8(const float* __restrict__ p) {
    F8 r;
    float4 a = *(const float4*)p;
    float4 b = *(const float4*)(p + 4);
    r.v[0]=a.x; r.v[1]=a.y; r.v[2]=a.z; r.v[3]=a.w;
    r.v[4]=b.x; r.v[5]=b.y; r.v[6]=b.z; r.v[7]=b.w;
    return r;
}

// ---- Kernel B: conv + LN + linear + sigmoid -> alpha[B,T] ----
// Wave = 4 consecutive t. Waves fully beyond input_length write zeros, no loads.
__global__ __launch_bounds__(256) void k_alpha(
    const float* __restrict__ enc, const float* __restrict__ convw,
    const float* __restrict__ gamma, const float* __restrict__ beta,
    const float* __restrict__ projw, const float* __restrict__ projb,
    const int* __restrict__ ilen, float* __restrict__ alpha_out)
{
    const int NB = 188;  // blocks per batch
    int wave = threadIdx.x >> 6;
    int lane = threadIdx.x & 63;
    int b  = blockIdx.x / NB;
    int tb = blockIdx.x % NB;
    int t0 = tb * 16 + wave * 4;          // this wave: t0 .. t0+3
    int d0 = lane * 8;
    if (t0 >= T_) return;

    int il = ilen[b];                     // uniform scalar load
    if (t0 >= il) {                       // whole wave masked: zeros, no enc loads
        if (lane == 0) {
#pragma unroll
            for (int q = 0; q < 4; ++q) {
                int t = t0 + q;
                if (t < T_) alpha_out[b * T_ + t] = 0.0f;
            }
        }
        return;
    }

    const float* rowp = enc + ((size_t)b * T_ + t0) * D_ + d0;

    F8 r[6];
#pragma unroll
    for (int i = 0; i < 6; ++i) {
        int t = t0 - 1 + i;
        if (t >= 0 && t < T_) r[i] = load8(rowp + (ptrdiff_t)(i - 1) * D_);
        else { for (int j = 0; j < 8; ++j) r[i].v[j] = 0.f; }
    }

    float w24[24];
    const float4* wp = (const float4*)(convw + (size_t)d0 * 3);
#pragma unroll
    for (int i = 0; i < 6; ++i) {
        float4 q = wp[i];
        w24[4*i+0]=q.x; w24[4*i+1]=q.y; w24[4*i+2]=q.z; w24[4*i+3]=q.w;
    }
    F8 pw = load8(projw + d0);
    F8 gm = load8(gamma + d0);
    F8 bt = load8(beta + d0);
    float pg[8];
    float c0p = 0.f, c1p = 0.f;
#pragma unroll
    for (int j = 0; j < 8; ++j) {
        pg[j] = pw.v[j] * gm.v[j];
        c0p += pw.v[j] * bt.v[j];
        c1p += pg[j];
    }

    float s1[4], s2[4], sp[4];
#pragma unroll
    for (int q = 0; q < 4; ++q) { s1[q]=0.f; s2[q]=0.f; sp[q]=0.f; }

#pragma unroll
    for (int q = 0; q < 4; ++q) {
#pragma unroll
        for (int j = 0; j < 8; ++j) {
            float y = r[q].v[j]*w24[3*j] + r[q+1].v[j]*w24[3*j+1] + r[q+2].v[j]*w24[3*j+2];
            s1[q] += y; s2[q] += y*y; sp[q] += pg[j]*y;
        }
    }
#pragma unroll
    for (int off = 1; off < 64; off <<= 1) {
#pragma unroll
        for (int q = 0; q < 4; ++q) {
            s1[q] += __shfl_xor(s1[q], off);
            s2[q] += __shfl_xor(s2[q], off);
            sp[q] += __shfl_xor(sp[q], off);
        }
        c0p += __shfl_xor(c0p, off);
        c1p += __shfl_xor(c1p, off);
    }
    if (lane == 0) {
        float c0 = c0p + projb[0];
        float c1 = c1p;
#pragma unroll
        for (int q = 0; q < 4; ++q) {
            int t = t0 + q;
            if (t >= T_) break;
            float mu  = s1[q] * (1.0f / D_);
            float var = s2[q] * (1.0f / D_) - mu * mu;
            float rsig = rsqrtf(var + LN_EPS);
            float logit = rsig * (sp[q] - mu * c1) + c0;
            float a = 1.0f / (1.0f + expf(-logit));
            if (t >= il) a = 0.0f;
            alpha_out[b * T_ + t] = a;
        }
    }
}

// ---- Kernel C: per-batch scan + scale + packed (start,end) per bin ----
__global__ __launch_bounds__(512) void k_prep(
    const float* __restrict__ alpha, const int* __restrict__ tlen,
    const int* __restrict__ ilen, float* __restrict__ ws)
{
    __shared__ float sc[T_];
    __shared__ float part[8];
    __shared__ int   sstg[452];

    int b = blockIdx.x;
    int tid = threadIdx.x;
    int wave = tid >> 6;
    int lane = tid & 63;

    float* cumg = ws + WS_CUM + (size_t)b * T_;
    int2*  aeg  = (int2*)(ws + WS_AE) + b * NTOK;

    // block-wide inclusive cumsum of alpha (unscaled)
    float run = 0.f;
    for (int base = 0; base < T_; base += 512) {
        int t = base + tid;
        float v = (t < T_) ? alpha[b * T_ + t] : 0.f;
#pragma unroll
        for (int off = 1; off < 64; off <<= 1) {
            float n = __shfl_up(v, off);
            if (lane >= off) v += n;
        }
        if (lane == 63) part[wave] = v;
        __syncthreads();
        float prefix = run;
        for (int w = 0; w < 8; ++w) {
            float pv = part[w];
            if (w < wave) prefix += pv;
            run += pv;
        }
        v += prefix;
        if (t < T_) sc[t] = v;
        __syncthreads();
    }

    float sum = run;               // identical in all threads
    float tgt = (float)tlen[b];
    float scale = tgt / fmaxf(sum, 1e-8f);
    if (tid == 0) ws[WS_DIFF + b] = fabsf(sum - tgt);

    // scale in LDS + write cum to global
    for (int t = tid; t < T_; t += 512) {
        float cv = sc[t] * scale;
        sc[t] = cv;
        cumg[t] = cv;
    }
    __syncthreads();

    // bin starts: sstg[k] = first t with cum[t] >= k, k in [0,449]
    for (int k = tid; k < 450; k += 512) {
        float vk = (float)k;
        int lo = 0, hi = T_;
        while (lo < hi) {
            int mid = (lo + hi) >> 1;
            if (sc[mid] < vk) lo = mid + 1; else hi = mid;
        }
        sstg[k] = lo;
    }
    __syncthreads();

    int il = ilen[b];
    for (int k = tid; k < NTOK; k += 512) {
        int a = sstg[k];
        int e = sstg[k + 1] + 1;
        if (e > il) e = il;
        aeg[k] = make_int2(a, e);
    }
}

// ---- Kernel E: gather, one WAVE per bin, branch-free inner loop ----
// Block = 4 waves = 4 bins. Grid = B*112 + 1 (last block: qty loss).
__global__ __launch_bounds__(256) void k_gather(
    const float* __restrict__ enc, const float* __restrict__ ws,
    float* __restrict__ out, float* __restrict__ qty)
{
    int bid = blockIdx.x;
    if (bid == B_ * 112) {               // qty block
        int lane = threadIdx.x;
        if (lane < 64) {
            float v = (lane < B_) ? ws[WS_DIFF + lane] : 0.f;
#pragma unroll
            for (int off = 1; off < 16; off <<= 1) v += __shfl_xor(v, off);
            if (lane == 0) *qty = v * (1.0f / B_);
        }
        return;
    }

    const int NBLK = NTOK / 4;  // 112
    int b  = bid / NBLK;
    int kg = bid % NBLK;
    int wave = threadIdx.x >> 6;
    int lane = threadIdx.x & 63;
    int k = kg * 4 + wave;

    const float* cb  = ws + WS_CUM + (size_t)b * T_;
    const int2*  aeg = (const int2*)(ws + WS_AE) + b * NTOK;

    int2 ae = aeg[k];
    int a = ae.x, e = ae.y;

    int d0 = lane * 8;
    const float* encb = enc + (size_t)b * T_ * D_ + d0;

    float4 aa = {0,0,0,0}, ab = {0,0,0,0};
    float fk = (float)k;

    for (int base = a; base < e; base += 63) {
        int n = e - base; if (n > 63) n = 63;
        // lane j (j<=n) holds cum[base-1+j]; weight of frame base+j for bin k:
        float cl = 0.0f;
        int t = base - 1 + lane;
        if (lane <= n && t >= 0) cl = cb[t];
        float cn = __shfl_down(cl, 1);
        float fklo = floorf(cl);
        float bnd  = fklo + 1.0f;
        float wlo  = fmaxf(fminf(cn, bnd) - cl, 0.0f);
        float whi  = fmaxf(cn - bnd, 0.0f);
        float wl = (fklo == fk ? wlo : 0.0f) + (floorf(cn) == fk ? whi : 0.0f);
        if (lane >= n) wl = 0.0f;

#pragma unroll 4
        for (int j = 0; j < n; ++j) {
            float w = __shfl(wl, j);
            const float* rp = encb + (size_t)(base + j) * D_;
            float4 ea = *(const float4*)rp;
            float4 eb = *(const float4*)(rp + 4);
            aa.x += ea.x*w; aa.y += ea.y*w; aa.z += ea.z*w; aa.w += ea.w*w;
            ab.x += eb.x*w; ab.y += eb.y*w; ab.z += eb.z*w; ab.w += eb.w*w;
        }
    }

    float* op = out + ((size_t)b * NTOK + k) * D_ + d0;
    *(float4*)op       = aa;
    *(float4*)(op + 4) = ab;
}

extern "C" void kernel_launch(void* const* d_in, const int* in_sizes, int n_in,
                              void* d_out, int out_size, void* d_ws, size_t ws_size,
                              hipStream_t stream) {
    const float* enc   = (const float*)d_in[0];
    const float* convw = (const float*)d_in[1];
    const float* gamma = (const float*)d_in[2];
    const float* beta  = (const float*)d_in[3];
    const float* projw = (const float*)d_in[4];
    const float* projb = (const float*)d_in[5];
    const int*   ilen  = (const int*)d_in[6];
    const int*   tlen  = (const int*)d_in[7];

    float* out_f     = (float*)d_out;                       // [B,448,D]
    float* alpha_out = out_f + (size_t)B_ * NTOK * D_;      // [B,T]
    float* qty_out   = alpha_out + (size_t)B_ * T_;         // scalar

    float* ws = (float*)d_ws;

    hipLaunchKernelGGL(k_alpha, dim3(B_ * 188), dim3(256), 0, stream,
                       enc, convw, gamma, beta, projw, projb, ilen, alpha_out);
    hipLaunchKernelGGL(k_prep, dim3(B_), dim3(512), 0, stream,
                       alpha_out, tlen, ilen, ws);
    hipLaunchKernelGGL(k_gather, dim3(B_ * 112 + 1), dim3(256), 0, stream,
                       enc, ws, out_f, qty_out);
}

// Round 6
// 47.204 us; speedup vs baseline: 6.4258x; 1.0184x over previous
//
#include <hip/hip_runtime.h>
#include <math.h>

#define B_ 16
#define T_ 3000
#define D_ 512
#define NTOK 448
#define LN_EPS 1e-5f

// ws layout (floats):
// [16..32)   diff[b] = |sum_alpha - tgt|
// [64..64+B*T)   cum[b][t]
// [64+B*T ..)    ae[b][448] (int2: start, end)
#define WS_DIFF 16
#define WS_CUM  64
#define WS_AE   (64 + B_ * T_)

struct F8 { float v[8]; };

__device__ inline F8 load8(const float* __restrict__ p) {
    F8 r;
    float4 a = *(const float4*)p;
    float4 b = *(const float4*)(p + 4);
    r.v[0]=a.x; r.v[1]=a.y; r.v[2]=a.z; r.v[3]=a.w;
    r.v[4]=b.x; r.v[5]=b.y; r.v[6]=b.z; r.v[7]=b.w;
    return r;
}

// async global->LDS, 16B per lane; dst is wave-uniform base, HW adds lane*16
__device__ inline void stage16(const float* src, float* dst) {
    __builtin_amdgcn_global_load_lds(
        (const __attribute__((address_space(1))) void*)src,
        (__attribute__((address_space(3))) void*)dst, 16, 0, 0);
}

// ---- Kernel B: conv + LN + linear + sigmoid -> alpha[B,T] ----
// Block = 256 thr = 16 t. Rows t0-1..t0+16 staged in LDS via global_load_lds
// (1.125x read amplification). Blocks fully beyond input_length write zeros.
__global__ __launch_bounds__(256) void k_alpha(
    const float* __restrict__ enc, const float* __restrict__ convw,
    const float* __restrict__ gamma, const float* __restrict__ beta,
    const float* __restrict__ projw, const float* __restrict__ projb,
    const int* __restrict__ ilen, float* __restrict__ alpha_out)
{
    const int NB = 188;  // blocks per batch (188*16 = 3008 >= T)
    int b  = blockIdx.x / NB;
    int tb = blockIdx.x % NB;
    int t0 = tb * 16;
    int tid = threadIdx.x;
    int wave = tid >> 6;
    int lane = tid & 63;

    int il = ilen[b];
    if (t0 >= il) {                      // whole block masked: zeros, no enc reads
        int t = t0 + tid;
        if (tid < 16 && t < T_) alpha_out[b * T_ + t] = 0.0f;
        return;
    }

    __shared__ float lds[18][512];       // rows t0-1 .. t0+16 (clamped)

    const float* encb = enc + (size_t)b * T_ * D_;
    for (int r = wave; r < 18; r += 4) {
        int t = t0 - 1 + r;
        t = t < 0 ? 0 : (t > T_ - 1 ? T_ - 1 : t);
        const float* src = encb + (size_t)t * D_ + lane * 4;
        stage16(src,       &lds[r][0]);
        stage16(src + 256, &lds[r][256]);
    }

    // per-lane weights while staging is in flight
    int d0 = lane * 8;
    float w24[24];
    const float4* wp = (const float4*)(convw + (size_t)d0 * 3);
#pragma unroll
    for (int i = 0; i < 6; ++i) {
        float4 q = wp[i];
        w24[4*i+0]=q.x; w24[4*i+1]=q.y; w24[4*i+2]=q.z; w24[4*i+3]=q.w;
    }
    F8 pw = load8(projw + d0);
    F8 gm = load8(gamma + d0);
    F8 bt = load8(beta + d0);
    float pg[8];
    float c0p = 0.f, c1p = 0.f;
#pragma unroll
    for (int j = 0; j < 8; ++j) {
        pg[j] = pw.v[j] * gm.v[j];
        c0p += pw.v[j] * bt.v[j];
        c1p += pg[j];
    }

    __syncthreads();                     // vmcnt(0) drain of DMA + barrier

    int w4 = wave * 4;                   // wave handles t = t0+w4 .. t0+w4+3
    float4 ra0 = *(const float4*)&lds[w4][d0];
    float4 ra1 = *(const float4*)&lds[w4][d0 + 4];
    float4 rb0 = *(const float4*)&lds[w4 + 1][d0];
    float4 rb1 = *(const float4*)&lds[w4 + 1][d0 + 4];

    float s1[4], s2[4], sp[4];
#pragma unroll
    for (int q = 0; q < 4; ++q) { s1[q]=0.f; s2[q]=0.f; sp[q]=0.f; }

#pragma unroll
    for (int q = 0; q < 4; ++q) {
        float4 rc0 = *(const float4*)&lds[w4 + q + 2][d0];
        float4 rc1 = *(const float4*)&lds[w4 + q + 2][d0 + 4];
        int t = t0 + w4 + q;
        float m0 = (t == 0)      ? 0.f : 1.f;   // conv zero-pad at edges
        float m2 = (t >= T_ - 1) ? 0.f : 1.f;
        float xm[8] = {ra0.x,ra0.y,ra0.z,ra0.w, ra1.x,ra1.y,ra1.z,ra1.w};
        float xc[8] = {rb0.x,rb0.y,rb0.z,rb0.w, rb1.x,rb1.y,rb1.z,rb1.w};
        float xp[8] = {rc0.x,rc0.y,rc0.z,rc0.w, rc1.x,rc1.y,rc1.z,rc1.w};
#pragma unroll
        for (int j = 0; j < 8; ++j) {
            float y = (xm[j]*m0)*w24[3*j] + xc[j]*w24[3*j+1] + (xp[j]*m2)*w24[3*j+2];
            s1[q] += y; s2[q] += y*y; sp[q] += pg[j]*y;
        }
        ra0 = rb0; ra1 = rb1; rb0 = rc0; rb1 = rc1;
    }

#pragma unroll
    for (int off = 1; off < 64; off <<= 1) {
#pragma unroll
        for (int q = 0; q < 4; ++q) {
            s1[q] += __shfl_xor(s1[q], off);
            s2[q] += __shfl_xor(s2[q], off);
            sp[q] += __shfl_xor(sp[q], off);
        }
        c0p += __shfl_xor(c0p, off);
        c1p += __shfl_xor(c1p, off);
    }
    if (lane == 0) {
        float c0 = c0p + projb[0];
        float c1 = c1p;
#pragma unroll
        for (int q = 0; q < 4; ++q) {
            int t = t0 + w4 + q;
            if (t >= T_) break;
            float mu  = s1[q] * (1.0f / D_);
            float var = s2[q] * (1.0f / D_) - mu * mu;
            float rsig = rsqrtf(var + LN_EPS);
            float logit = rsig * (sp[q] - mu * c1) + c0;
            float a = 1.0f / (1.0f + expf(-logit));
            if (t >= il) a = 0.0f;
            alpha_out[b * T_ + t] = a;
        }
    }
}

// ---- Kernel C: per-batch scan + scale + packed (start,end) per bin ----
__global__ __launch_bounds__(1024) void k_prep(
    const float* __restrict__ alpha, const int* __restrict__ tlen,
    const int* __restrict__ ilen, float* __restrict__ ws)
{
    __shared__ float sc[T_];
    __shared__ float part[16];
    __shared__ int   sstg[452];

    int b = blockIdx.x;
    int tid = threadIdx.x;
    int wave = tid >> 6;
    int lane = tid & 63;

    float* cumg = ws + WS_CUM + (size_t)b * T_;
    int2*  aeg  = (int2*)(ws + WS_AE) + b * NTOK;

    // block-wide inclusive cumsum of alpha (unscaled), 3 chunks of 1024
    float run = 0.f;
    for (int base = 0; base < T_; base += 1024) {
        int t = base + tid;
        float v = (t < T_) ? alpha[b * T_ + t] : 0.f;
#pragma unroll
        for (int off = 1; off < 64; off <<= 1) {
            float n = __shfl_up(v, off);
            if (lane >= off) v += n;
        }
        if (lane == 63) part[wave] = v;
        __syncthreads();
        float prefix = run;
        for (int w = 0; w < 16; ++w) {
            float pv = part[w];
            if (w < wave) prefix += pv;
            run += pv;
        }
        v += prefix;
        if (t < T_) sc[t] = v;
        __syncthreads();
    }

    float sum = run;               // identical in all threads
    float tgt = (float)tlen[b];
    float scale = tgt / fmaxf(sum, 1e-8f);
    if (tid == 0) ws[WS_DIFF + b] = fabsf(sum - tgt);

    // scale in LDS + write cum to global
    for (int t = tid; t < T_; t += 1024) {
        float cv = sc[t] * scale;
        sc[t] = cv;
        cumg[t] = cv;
    }
    __syncthreads();

    // bin starts: sstg[k] = first t with cum[t] >= k, k in [0,449]
    if (tid < 450) {
        float vk = (float)tid;
        int lo = 0, hi = T_;
        while (lo < hi) {
            int mid = (lo + hi) >> 1;
            if (sc[mid] < vk) lo = mid + 1; else hi = mid;
        }
        sstg[tid] = lo;
    }
    __syncthreads();

    int il = ilen[b];
    if (tid < NTOK) {
        int a = sstg[tid];
        int e = sstg[tid + 1] + 1;
        if (e > il) e = il;
        aeg[tid] = make_int2(a, e);
    }
}

// ---- Kernel E: gather, one WAVE per bin, branch-free inner loop ----
// Block = 4 waves = 4 bins. Grid = B*112 + 1 (last block: qty loss).
__global__ __launch_bounds__(256) void k_gather(
    const float* __restrict__ enc, const float* __restrict__ ws,
    float* __restrict__ out, float* __restrict__ qty)
{
    int bid = blockIdx.x;
    if (bid == B_ * 112) {               // qty block
        int lane = threadIdx.x;
        if (lane < 64) {
            float v = (lane < B_) ? ws[WS_DIFF + lane] : 0.f;
#pragma unroll
            for (int off = 1; off < 16; off <<= 1) v += __shfl_xor(v, off);
            if (lane == 0) *qty = v * (1.0f / B_);
        }
        return;
    }

    const int NBLK = NTOK / 4;  // 112
    int b  = bid / NBLK;
    int kg = bid % NBLK;
    int wave = threadIdx.x >> 6;
    int lane = threadIdx.x & 63;
    int k = kg * 4 + wave;

    const float* cb  = ws + WS_CUM + (size_t)b * T_;
    const int2*  aeg = (const int2*)(ws + WS_AE) + b * NTOK;

    int2 ae = aeg[k];
    int a = ae.x, e = ae.y;

    int d0 = lane * 8;
    const float* encb = enc + (size_t)b * T_ * D_ + d0;

    float4 aa = {0,0,0,0}, ab = {0,0,0,0};
    float fk = (float)k;

    for (int base = a; base < e; base += 63) {
        int n = e - base; if (n > 63) n = 63;
        // lane j (j<=n) holds cum[base-1+j]; weight of frame base+j for bin k:
        float cl = 0.0f;
        int t = base - 1 + lane;
        if (lane <= n && t >= 0) cl = cb[t];
        float cn = __shfl_down(cl, 1);
        float fklo = floorf(cl);
        float bnd  = fklo + 1.0f;
        float wlo  = fmaxf(fminf(cn, bnd) - cl, 0.0f);
        float whi  = fmaxf(cn - bnd, 0.0f);
        float wl = (fklo == fk ? wlo : 0.0f) + (floorf(cn) == fk ? whi : 0.0f);
        if (lane >= n) wl = 0.0f;

#pragma unroll 4
        for (int j = 0; j < n; ++j) {
            float w = __shfl(wl, j);
            const float* rp = encb + (size_t)(base + j) * D_;
            float4 ea = *(const float4*)rp;
            float4 eb = *(const float4*)(rp + 4);
            aa.x += ea.x*w; aa.y += ea.y*w; aa.z += ea.z*w; aa.w += ea.w*w;
            ab.x += eb.x*w; ab.y += eb.y*w; ab.z += eb.z*w; ab.w += eb.w*w;
        }
    }

    float* op = out + ((size_t)b * NTOK + k) * D_ + d0;
    *(float4*)op       = aa;
    *(float4*)(op + 4) = ab;
}

extern "C" void kernel_launch(void* const* d_in, const int* in_sizes, int n_in,
                              void* d_out, int out_size, void* d_ws, size_t ws_size,
                              hipStream_t stream) {
    const float* enc   = (const float*)d_in[0];
    const float* convw = (const float*)d_in[1];
    const float* gamma = (const float*)d_in[2];
    const float* beta  = (const float*)d_in[3];
    const float* projw = (const float*)d_in[4];
    const float* projb = (const float*)d_in[5];
    const int*   ilen  = (const int*)d_in[6];
    const int*   tlen  = (const int*)d_in[7];

    float* out_f     = (float*)d_out;                       // [B,448,D]
    float* alpha_out = out_f + (size_t)B_ * NTOK * D_;      // [B,T]
    float* qty_out   = alpha_out + (size_t)B_ * T_;         // scalar

    float* ws = (float*)d_ws;

    hipLaunchKernelGGL(k_alpha, dim3(B_ * 188), dim3(256), 0, stream,
                       enc, convw, gamma, beta, projw, projb, ilen, alpha_out);
    hipLaunchKernelGGL(k_prep, dim3(B_), dim3(1024), 0, stream,
                       alpha_out, tlen, ilen, ws);
    hipLaunchKernelGGL(k_gather, dim3(B_ * 112 + 1), dim3(256), 0, stream,
                       enc, ws, out_f, qty_out);
}